// Round 1
// baseline (788.640 us; speedup 1.0000x reference)
//
#include <hip/hip_runtime.h>
#include <hip/hip_bf16.h>

#define B_   2
#define T_   2048
#define D_   1024
#define NH_  16
#define HD_  64
#define HID_ 4096
#define CD_  1024
#define SIX_D (6*D_)

typedef __bf16 bf16x8 __attribute__((ext_vector_type(8)));
typedef float  f32x4  __attribute__((ext_vector_type(4)));

__device__ __forceinline__ unsigned short f2bf(float f){
  union { float f; unsigned u; } v; v.f = f;
  unsigned r = v.u + 0x7FFFu + ((v.u >> 16) & 1u);
  return (unsigned short)(r >> 16);
}

__device__ __forceinline__ void gl_lds16(const void* g, void* l){
  __builtin_amdgcn_global_load_lds(
      (__attribute__((address_space(1))) void*)const_cast<void*>(g),
      (__attribute__((address_space(3))) void*)l, 16, 0, 0);
}

// ---------------- fp32 -> bf16 convert ----------------
__global__ void k_conv_bf16(const float* __restrict__ in, unsigned short* __restrict__ out, int n4){
  int i = blockIdx.x*256 + threadIdx.x;
  if (i >= n4) return;
  float4 v = reinterpret_cast<const float4*>(in)[i];
  ushort4 o;
  o.x = f2bf(v.x); o.y = f2bf(v.y); o.z = f2bf(v.z); o.w = f2bf(v.w);
  reinterpret_cast<ushort4*>(out)[i] = o;
}

// ---------------- ada = silu(cond) @ ada_w.T + ada_b ----------------
__global__ void k_ada(const float* __restrict__ cond, const float* __restrict__ ada_w,
                      const float* __restrict__ ada_b, float* __restrict__ ada){
  __shared__ float sc[CD_];
  int b = blockIdx.y;
  int tid = threadIdx.x;
  for (int i = tid; i < CD_; i += 256){
    float c = cond[b*CD_ + i];
    sc[i] = c / (1.f + __expf(-c));
  }
  __syncthreads();
  int col = blockIdx.x*256 + tid;
  const float* wr = ada_w + (size_t)col*CD_;
  float acc = 0.f;
  #pragma unroll 4
  for (int k = 0; k < CD_; k++) acc += sc[k]*wr[k];
  ada[b*SIX_D + col] = acc + ada_b[col];
}

// ---------------- rmsnorm + modulate -> bf16 ----------------
__global__ void k_norm_mod(const float* __restrict__ x, const float* __restrict__ w,
                           const float* __restrict__ ada, int sh_off, int sc_off,
                           unsigned short* __restrict__ out){
  int row = blockIdx.x;           // b*T + t
  int b = row >> 11;              // / T_
  int tid = threadIdx.x;
  float4 xv = reinterpret_cast<const float4*>(x + (size_t)row*D_)[tid];
  float ss = xv.x*xv.x + xv.y*xv.y + xv.z*xv.z + xv.w*xv.w;
  #pragma unroll
  for (int m = 32; m > 0; m >>= 1) ss += __shfl_xor(ss, m, 64);
  __shared__ float red[4];
  int wave = tid >> 6;
  if ((tid & 63) == 0) red[wave] = ss;
  __syncthreads();
  float tot = red[0]+red[1]+red[2]+red[3];
  float rn = rsqrtf(tot * (1.f/(float)D_) + 1e-6f);
  float4 wv  = reinterpret_cast<const float4*>(w)[tid];
  float4 scv = reinterpret_cast<const float4*>(ada + b*SIX_D + sc_off)[tid];
  float4 shv = reinterpret_cast<const float4*>(ada + b*SIX_D + sh_off)[tid];
  ushort4 o;
  o.x = f2bf(xv.x*rn*wv.x*(1.f+scv.x)+shv.x);
  o.y = f2bf(xv.y*rn*wv.y*(1.f+scv.y)+shv.y);
  o.z = f2bf(xv.z*rn*wv.z*(1.f+scv.z)+shv.z);
  o.w = f2bf(xv.w*rn*wv.w*(1.f+scv.w)+shv.w);
  reinterpret_cast<ushort4*>(out + (size_t)row*D_)[tid] = o;
}

// ---------------- generic GEMM: C = A(MxK) * W(NxK)^T, bf16 in, epilogues ----------------
enum { EPI_F32 = 0, EPI_RESID = 1 };

template<int EPI>
__launch_bounds__(256)
__global__ void k_gemm_bt(const unsigned short* __restrict__ A,
                          const unsigned short* __restrict__ W,
                          int M, int N, int K,
                          float* __restrict__ outf,
                          const float* __restrict__ resid,
                          const float* __restrict__ ada, int g_off,
                          const float* __restrict__ bias){
  __shared__ __align__(16) unsigned short As[128*32];
  __shared__ __align__(16) unsigned short Bs[128*32];
  const int tid = threadIdx.x;
  const int wave = tid >> 6, lane = tid & 63;
  const int wm = (wave >> 1)*64, wn = (wave & 1)*64;
  const int m0 = blockIdx.y*128, n0 = blockIdx.x*128;
  const int fr = lane & 15, fq = lane >> 4;
  f32x4 acc[4][4] = {};
  for (int k0 = 0; k0 < K; k0 += 32){
    __syncthreads();
    #pragma unroll
    for (int rr = 0; rr < 2; rr++){
      int idx = rr*256 + tid;
      int row = idx >> 2, c8 = (idx & 3)*8;
      gl_lds16(A + (size_t)(m0 + row)*K + k0 + c8, &As[(idx & ~63)*8]);
      gl_lds16(W + (size_t)(n0 + row)*K + k0 + c8, &Bs[(idx & ~63)*8]);
    }
    __syncthreads();
    bf16x8 af[4], bfr[4];
    #pragma unroll
    for (int i = 0; i < 4; i++){
      af[i]  = *(const bf16x8*)&As[(wm + i*16 + fr)*32 + fq*8];
      bfr[i] = *(const bf16x8*)&Bs[(wn + i*16 + fr)*32 + fq*8];
    }
    #pragma unroll
    for (int i = 0; i < 4; i++)
      #pragma unroll
      for (int j = 0; j < 4; j++)
        acc[i][j] = __builtin_amdgcn_mfma_f32_16x16x32_bf16(af[i], bfr[j], acc[i][j], 0,0,0);
  }
  #pragma unroll
  for (int i = 0; i < 4; i++){
    #pragma unroll
    for (int j = 0; j < 4; j++){
      int col = n0 + wn + j*16 + fr;
      #pragma unroll
      for (int r = 0; r < 4; r++){
        int row = m0 + wm + i*16 + fq*4 + r;
        float v = acc[i][j][r];
        if (EPI == EPI_F32){
          outf[(size_t)row*N + col] = v;
        } else {
          int b = row >> 11;   // row / T_
          float g = ada[b*SIX_D + g_off + col];
          outf[(size_t)row*N + col] = resid[(size_t)row*N + col] + g*(v + bias[col]);
        }
      }
    }
  }
}

// ---------------- fc1 dual (value+gate) with fused SwiGLU -> bf16 ----------------
__launch_bounds__(256)
__global__ void k_gemm_fc1(const unsigned short* __restrict__ A,
                           const unsigned short* __restrict__ W,   // (2*HID, D) bf16
                           const float* __restrict__ bias,          // (2*HID)
                           unsigned short* __restrict__ out){       // (B*T, HID) bf16
  __shared__ __align__(16) unsigned short As[128*32];
  __shared__ __align__(16) unsigned short Bv[128*32];
  __shared__ __align__(16) unsigned short Bg[128*32];
  const int K = D_;
  const int tid = threadIdx.x;
  const int wave = tid >> 6, lane = tid & 63;
  const int wm = (wave >> 1)*64, wn = (wave & 1)*64;
  const int m0 = blockIdx.y*128, n0 = blockIdx.x*128;
  const int fr = lane & 15, fq = lane >> 4;
  f32x4 accv[4][4] = {}, accg[4][4] = {};
  for (int k0 = 0; k0 < K; k0 += 32){
    __syncthreads();
    #pragma unroll
    for (int rr = 0; rr < 2; rr++){
      int idx = rr*256 + tid;
      int row = idx >> 2, c8 = (idx & 3)*8;
      gl_lds16(A + (size_t)(m0 + row)*K + k0 + c8,           &As[(idx & ~63)*8]);
      gl_lds16(W + (size_t)(n0 + row)*K + k0 + c8,           &Bv[(idx & ~63)*8]);
      gl_lds16(W + (size_t)(HID_ + n0 + row)*K + k0 + c8,    &Bg[(idx & ~63)*8]);
    }
    __syncthreads();
    bf16x8 af[4], bv[4], bg[4];
    #pragma unroll
    for (int i = 0; i < 4; i++){
      af[i] = *(const bf16x8*)&As[(wm + i*16 + fr)*32 + fq*8];
      bv[i] = *(const bf16x8*)&Bv[(wn + i*16 + fr)*32 + fq*8];
      bg[i] = *(const bf16x8*)&Bg[(wn + i*16 + fr)*32 + fq*8];
    }
    #pragma unroll
    for (int i = 0; i < 4; i++)
      #pragma unroll
      for (int j = 0; j < 4; j++){
        accv[i][j] = __builtin_amdgcn_mfma_f32_16x16x32_bf16(af[i], bv[j], accv[i][j], 0,0,0);
        accg[i][j] = __builtin_amdgcn_mfma_f32_16x16x32_bf16(af[i], bg[j], accg[i][j], 0,0,0);
      }
  }
  #pragma unroll
  for (int i = 0; i < 4; i++){
    #pragma unroll
    for (int j = 0; j < 4; j++){
      int col = n0 + wn + j*16 + fr;
      #pragma unroll
      for (int r = 0; r < 4; r++){
        int row = m0 + wm + i*16 + fq*4 + r;
        float vv = accv[i][j][r] + bias[col];
        float gg = accg[i][j][r] + bias[HID_ + col];
        float h = vv * (gg / (1.f + __expf(-gg)));
        out[(size_t)row*HID_ + col] = f2bf(h);
      }
    }
  }
}

// ---------------- qkv -> q,k,v with per-head rmsnorm + rope -> bf16 (B,NH,T,HD) ----------------
__global__ void k_qkv_post(const float* __restrict__ qkv,
                           const float* __restrict__ qw, const float* __restrict__ kw,
                           const int* __restrict__ wptr,
                           unsigned short* __restrict__ q, unsigned short* __restrict__ k,
                           unsigned short* __restrict__ v){
  int idx = blockIdx.x;           // (b*T + t)*NH + h
  int h = idx & (NH_-1);
  int t = (idx >> 4) & (T_-1);
  int b = idx >> 15;
  int d = threadIdx.x;            // 0..63
  const float* base = qkv + (size_t)(b*T_ + t)*3072;
  float qv = base[h*64 + d];
  float kv = base[1024 + h*64 + d];
  float vv = base[2048 + h*64 + d];
  float sq = qv*qv, sk = kv*kv;
  #pragma unroll
  for (int m = 32; m > 0; m >>= 1){ sq += __shfl_xor(sq, m, 64); sk += __shfl_xor(sk, m, 64); }
  qv *= rsqrtf(sq*(1.f/64.f) + 1e-6f) * qw[d];
  kv *= rsqrtf(sk*(1.f/64.f) + 1e-6f) * kw[d];
  int width = wptr[0];
  int yy = t / width, xx = t - yy*width;
  int coord = (d < 32) ? yy : xx;
  int fi = (d & 31) >> 1;
  float ifreq = __expf(-(float)fi * (9.210340371976184f/16.f));  // 10000^(-fi/16)
  float ang = (float)coord * ifreq;
  float cs = cosf(ang), sn = sinf(ang);
  float pq = __shfl_xor(qv, 1, 64);
  float pk = __shfl_xor(kv, 1, 64);
  float rq = (d & 1) ? pq : -pq;
  float rk = (d & 1) ? pk : -pk;
  qv = qv*cs + rq*sn;
  kv = kv*cs + rk*sn;
  size_t o = ((size_t)(b*NH_ + h)*T_ + t)*64 + d;
  q[o] = f2bf(qv); k[o] = f2bf(kv); v[o] = f2bf(vv);
}

// ---------------- flash attention (MFMA), writes (B,T,D) bf16 ----------------
__launch_bounds__(256)
__global__ void k_attn(const unsigned short* __restrict__ q,
                       const unsigned short* __restrict__ k,
                       const unsigned short* __restrict__ v,
                       unsigned short* __restrict__ out){
  __shared__ __align__(16) unsigned short Qs[128*64];
  __shared__ __align__(16) unsigned short Ks[64*64];
  __shared__ __align__(16) unsigned short Vt[64*64];   // Vt[d][kpos]
  __shared__ __align__(16) unsigned short Ps[4][32*64];
  const int tid = threadIdx.x;
  const int wave = tid >> 6, lane = tid & 63;
  const int fr = lane & 15, fq = lane >> 4;
  const int bh = blockIdx.y;
  const int q0 = blockIdx.x*128;
  const unsigned short* qb = q + (size_t)bh*T_*HD_;
  const unsigned short* kb = k + (size_t)bh*T_*HD_;
  const unsigned short* vb = v + (size_t)bh*T_*HD_;
  {
    const uint4* src = (const uint4*)(qb + (size_t)q0*HD_);
    uint4* dst = (uint4*)Qs;
    #pragma unroll
    for (int it = 0; it < 4; it++) dst[it*256 + tid] = src[it*256 + tid];
  }
  f32x4 o_acc[2][4] = {};
  float mrow[2][4], lrow[2][4];
  #pragma unroll
  for (int i=0;i<2;i++)
    #pragma unroll
    for (int r=0;r<4;r++){ mrow[i][r] = -1e30f; lrow[i][r] = 0.f; }
  for (int kt = 0; kt < T_; kt += 64){
    __syncthreads();
    {
      const uint4* src = (const uint4*)(kb + (size_t)kt*HD_);
      uint4* dst = (uint4*)Ks;
      #pragma unroll
      for (int it = 0; it < 2; it++) dst[it*256 + tid] = src[it*256 + tid];
    }
    {
      const ushort2* src = (const ushort2*)(vb + (size_t)kt*HD_);
      #pragma unroll
      for (int it = 0; it < 8; it++){
        int i2 = it*256 + tid;       // 0..2047
        int j  = i2 >> 5;            // kpos
        int dp = (i2 & 31)*2;        // d
        ushort2 val = src[i2];
        Vt[dp*64 + j]     = val.x;
        Vt[(dp+1)*64 + j] = val.y;
      }
    }
    __syncthreads();
    // S = Q K^T (rows wave*32..+31, cols kt..kt+63)
    f32x4 s[2][4] = {};
    #pragma unroll
    for (int kk = 0; kk < 2; kk++){
      bf16x8 aq[2], bk[4];
      #pragma unroll
      for (int i = 0; i < 2; i++)
        aq[i] = *(const bf16x8*)&Qs[(wave*32 + i*16 + fr)*64 + kk*32 + fq*8];
      #pragma unroll
      for (int j = 0; j < 4; j++)
        bk[j] = *(const bf16x8*)&Ks[(j*16 + fr)*64 + kk*32 + fq*8];
      #pragma unroll
      for (int i = 0; i < 2; i++)
        #pragma unroll
        for (int j = 0; j < 4; j++)
          s[i][j] = __builtin_amdgcn_mfma_f32_16x16x32_bf16(aq[i], bk[j], s[i][j], 0,0,0);
    }
    #pragma unroll
    for (int i=0;i<2;i++)
      #pragma unroll
      for (int j=0;j<4;j++) s[i][j] *= 0.125f;   // HD^-0.5
    unsigned short* Pw = Ps[wave];
    float alpha[2][4];
    #pragma unroll
    for (int i = 0; i < 2; i++){
      #pragma unroll
      for (int r = 0; r < 4; r++){
        float mx = -1e30f;
        #pragma unroll
        for (int j = 0; j < 4; j++) mx = fmaxf(mx, s[i][j][r]);
        #pragma unroll
        for (int m = 8; m > 0; m >>= 1) mx = fmaxf(mx, __shfl_xor(mx, m, 64));
        float mn = fmaxf(mrow[i][r], mx);
        float al = __expf(mrow[i][r] - mn);
        mrow[i][r] = mn;
        float rs = 0.f;
        #pragma unroll
        for (int j = 0; j < 4; j++){
          float p = __expf(s[i][j][r] - mn);
          s[i][j][r] = p;
          rs += p;
        }
        #pragma unroll
        for (int m = 8; m > 0; m >>= 1) rs += __shfl_xor(rs, m, 64);
        lrow[i][r] = lrow[i][r]*al + rs;
        alpha[i][r] = al;
        #pragma unroll
        for (int j = 0; j < 4; j++)
          Pw[(i*16 + fq*4 + r)*64 + j*16 + fr] = f2bf(s[i][j][r]);
      }
    }
    #pragma unroll
    for (int i=0;i<2;i++)
      #pragma unroll
      for (int dn=0;dn<4;dn++)
        #pragma unroll
        for (int r=0;r<4;r++)
          o_acc[i][dn][r] *= alpha[i][r];
    #pragma unroll
    for (int kk = 0; kk < 2; kk++){
      bf16x8 ap[2], bvv[4];
      #pragma unroll
      for (int i = 0; i < 2; i++)
        ap[i] = *(const bf16x8*)&Pw[(i*16 + fr)*64 + kk*32 + fq*8];
      #pragma unroll
      for (int dn = 0; dn < 4; dn++)
        bvv[dn] = *(const bf16x8*)&Vt[(dn*16 + fr)*64 + kk*32 + fq*8];
      #pragma unroll
      for (int i = 0; i < 2; i++)
        #pragma unroll
        for (int dn = 0; dn < 4; dn++)
          o_acc[i][dn] = __builtin_amdgcn_mfma_f32_16x16x32_bf16(ap[i], bvv[dn], o_acc[i][dn], 0,0,0);
    }
  }
  const int b = bh >> 4, h = bh & 15;
  #pragma unroll
  for (int i = 0; i < 2; i++){
    #pragma unroll
    for (int r = 0; r < 4; r++){
      float inv = 1.f / lrow[i][r];
      int trow = q0 + wave*32 + i*16 + fq*4 + r;
      size_t o = ((size_t)(b*T_ + trow))*D_ + h*64;
      #pragma unroll
      for (int dn = 0; dn < 4; dn++)
        out[o + dn*16 + fr] = f2bf(o_acc[i][dn][r] * inv);
    }
  }
}

extern "C" void kernel_launch(void* const* d_in, const int* in_sizes, int n_in,
                              void* d_out, int out_size, void* d_ws, size_t ws_size,
                              hipStream_t stream){
  const float* x      = (const float*)d_in[0];
  const float* cond   = (const float*)d_in[1];
  const float* norm1w = (const float*)d_in[2];
  const float* qkv_w  = (const float*)d_in[3];
  const float* q_nw   = (const float*)d_in[4];
  const float* k_nw   = (const float*)d_in[5];
  const float* proj_w = (const float*)d_in[6];
  const float* proj_b = (const float*)d_in[7];
  const float* norm2w = (const float*)d_in[8];
  const float* fc1_w  = (const float*)d_in[9];
  const float* fc1_b  = (const float*)d_in[10];
  const float* fc2_w  = (const float*)d_in[11];
  const float* fc2_b  = (const float*)d_in[12];
  const float* ada_w  = (const float*)d_in[13];
  const float* ada_b  = (const float*)d_in[14];
  const int*   wptr   = (const int*)d_in[16];
  float* out = (float*)d_out;

  char* ws = (char*)d_ws;
  size_t off = 0;
  auto alloc = [&](size_t bytes)->void*{
    void* p = ws + off; off += (bytes + 255) & ~(size_t)255; return p;
  };
  unsigned short* w_qkv  = (unsigned short*)alloc(3072ull*1024*2);
  unsigned short* w_proj = (unsigned short*)alloc(1024ull*1024*2);
  unsigned short* w_fc1  = (unsigned short*)alloc(8192ull*1024*2);
  unsigned short* w_fc2  = (unsigned short*)alloc(1024ull*4096*2);
  float* ada             = (float*)alloc((size_t)B_*SIX_D*4);
  unsigned short* h1     = (unsigned short*)alloc(4096ull*1024*2);
  char* qkvregion        = (char*)alloc(4096ull*3072*4);
  float* qkv_out         = (float*)qkvregion;
  unsigned short* attn_o = (unsigned short*)qkvregion;               // reuse (qkv dead)
  float* x1              = (float*)(qkvregion + 8388608);            // after attn_o
  unsigned short* qb     = (unsigned short*)alloc(32ull*2048*64*2);
  unsigned short* kb     = (unsigned short*)alloc(32ull*2048*64*2);
  unsigned short* vb     = (unsigned short*)alloc(32ull*2048*64*2);
  unsigned short* mlp    = (unsigned short*)alloc(4096ull*4096*2);
  (void)ws_size; (void)in_sizes; (void)n_in; (void)out_size;

  // weights -> bf16
  k_conv_bf16<<<3072, 256, 0, stream>>>(qkv_w,  w_qkv,  3072*1024/4);
  k_conv_bf16<<<1024, 256, 0, stream>>>(proj_w, w_proj, 1024*1024/4);
  k_conv_bf16<<<8192, 256, 0, stream>>>(fc1_w,  w_fc1,  8192*1024/4);
  k_conv_bf16<<<4096, 256, 0, stream>>>(fc2_w,  w_fc2,  4096*1024/4);

  k_ada<<<dim3(SIX_D/256, B_), 256, 0, stream>>>(cond, ada_w, ada_b, ada);
  k_norm_mod<<<B_*T_, 256, 0, stream>>>(x, norm1w, ada, 0, D_, h1);
  k_gemm_bt<EPI_F32><<<dim3(3072/128, 4096/128), 256, 0, stream>>>(
      h1, w_qkv, B_*T_, 3*D_, D_, qkv_out, nullptr, nullptr, 0, nullptr);
  k_qkv_post<<<B_*T_*NH_, 64, 0, stream>>>(qkv_out, q_nw, k_nw, wptr, qb, kb, vb);
  k_attn<<<dim3(T_/128, B_*NH_), 256, 0, stream>>>(qb, kb, vb, attn_o);
  k_gemm_bt<EPI_RESID><<<dim3(1024/128, 4096/128), 256, 0, stream>>>(
      attn_o, w_proj, B_*T_, D_, D_, x1, x, ada, 2*D_, proj_b);
  k_norm_mod<<<B_*T_, 256, 0, stream>>>(x1, norm2w, ada, 3*D_, 4*D_, h1);
  k_gemm_fc1<<<dim3(4096/128, 4096/128), 256, 0, stream>>>(h1, w_fc1, fc1_b, mlp);
  k_gemm_bt<EPI_RESID><<<dim3(1024/128, 4096/128), 256, 0, stream>>>(
      mlp, w_fc2, B_*T_, D_, HID_, out, x1, ada, 5*D_, fc2_b);
}

// Round 2
// 701.861 us; speedup vs baseline: 1.1236x; 1.1236x over previous
//
#include <hip/hip_runtime.h>
#include <hip/hip_bf16.h>

#define B_   2
#define T_   2048
#define D_   1024
#define NH_  16
#define HD_  64
#define HID_ 4096
#define CD_  1024
#define SIX_D (6*D_)

typedef __bf16 bf16x8 __attribute__((ext_vector_type(8)));
typedef float  f32x4  __attribute__((ext_vector_type(4)));

__device__ __forceinline__ unsigned short f2bf(float f){
  union { float f; unsigned u; } v; v.f = f;
  unsigned r = v.u + 0x7FFFu + ((v.u >> 16) & 1u);
  return (unsigned short)(r >> 16);
}
__device__ __forceinline__ float bf2f(unsigned short u){
  union { unsigned x; float f; } v; v.x = ((unsigned)u) << 16; return v.f;
}

__device__ __forceinline__ void gl_lds16(const void* g, void* l){
  __builtin_amdgcn_global_load_lds(
      (__attribute__((address_space(1))) void*)const_cast<void*>(g),
      (__attribute__((address_space(3))) void*)l, 16, 0, 0);
}

// ---------------- fp32 -> bf16 convert ----------------
__global__ void k_conv_bf16(const float* __restrict__ in, unsigned short* __restrict__ out, int n4){
  int i = blockIdx.x*256 + threadIdx.x;
  if (i >= n4) return;
  float4 v = reinterpret_cast<const float4*>(in)[i];
  ushort4 o;
  o.x = f2bf(v.x); o.y = f2bf(v.y); o.z = f2bf(v.z); o.w = f2bf(v.w);
  reinterpret_cast<ushort4*>(out)[i] = o;
}

// ---------------- ada = silu(cond) @ ada_w.T + ada_b ----------------
__global__ void k_ada(const float* __restrict__ cond, const float* __restrict__ ada_w,
                      const float* __restrict__ ada_b, float* __restrict__ ada){
  __shared__ float sc[CD_];
  int b = blockIdx.y;
  int tid = threadIdx.x;
  for (int i = tid; i < CD_; i += 256){
    float c = cond[b*CD_ + i];
    sc[i] = c / (1.f + __expf(-c));
  }
  __syncthreads();
  int col = blockIdx.x*256 + tid;
  const float* wr = ada_w + (size_t)col*CD_;
  float acc = 0.f;
  #pragma unroll 4
  for (int k = 0; k < CD_; k++) acc += sc[k]*wr[k];
  ada[b*SIX_D + col] = acc + ada_b[col];
}

// ---------------- rmsnorm + modulate -> bf16 ----------------
__global__ void k_norm_mod(const float* __restrict__ x, const float* __restrict__ w,
                           const float* __restrict__ ada, int sh_off, int sc_off,
                           unsigned short* __restrict__ out){
  int row = blockIdx.x;           // b*T + t
  int b = row >> 11;              // / T_
  int tid = threadIdx.x;
  float4 xv = reinterpret_cast<const float4*>(x + (size_t)row*D_)[tid];
  float ss = xv.x*xv.x + xv.y*xv.y + xv.z*xv.z + xv.w*xv.w;
  #pragma unroll
  for (int m = 32; m > 0; m >>= 1) ss += __shfl_xor(ss, m, 64);
  __shared__ float red[4];
  int wave = tid >> 6;
  if ((tid & 63) == 0) red[wave] = ss;
  __syncthreads();
  float tot = red[0]+red[1]+red[2]+red[3];
  float rn = rsqrtf(tot * (1.f/(float)D_) + 1e-6f);
  float4 wv  = reinterpret_cast<const float4*>(w)[tid];
  float4 scv = reinterpret_cast<const float4*>(ada + b*SIX_D + sc_off)[tid];
  float4 shv = reinterpret_cast<const float4*>(ada + b*SIX_D + sh_off)[tid];
  ushort4 o;
  o.x = f2bf(xv.x*rn*wv.x*(1.f+scv.x)+shv.x);
  o.y = f2bf(xv.y*rn*wv.y*(1.f+scv.y)+shv.y);
  o.z = f2bf(xv.z*rn*wv.z*(1.f+scv.z)+shv.z);
  o.w = f2bf(xv.w*rn*wv.w*(1.f+scv.w)+shv.w);
  reinterpret_cast<ushort4*>(out + (size_t)row*D_)[tid] = o;
}

// ---------------- generic GEMM: C = A(MxK) * W(NxK)^T, bf16 in, epilogues ----------------
enum { EPI_F32 = 0, EPI_RESID = 1 };

template<int EPI>
__launch_bounds__(256)
__global__ void k_gemm_bt(const unsigned short* __restrict__ A,
                          const unsigned short* __restrict__ W,
                          int M, int N, int K,
                          float* __restrict__ outf,
                          const float* __restrict__ resid,
                          const float* __restrict__ ada, int g_off,
                          const float* __restrict__ bias){
  __shared__ __align__(16) unsigned short As[128*32];
  __shared__ __align__(16) unsigned short Bs[128*32];
  const int tid = threadIdx.x;
  const int wave = tid >> 6, lane = tid & 63;
  const int wm = (wave >> 1)*64, wn = (wave & 1)*64;
  const int m0 = blockIdx.y*128, n0 = blockIdx.x*128;
  const int fr = lane & 15, fq = lane >> 4;
  f32x4 acc[4][4] = {};
  for (int k0 = 0; k0 < K; k0 += 32){
    __syncthreads();
    #pragma unroll
    for (int rr = 0; rr < 2; rr++){
      int idx = rr*256 + tid;
      int row = idx >> 2, c8 = (idx & 3)*8;
      gl_lds16(A + (size_t)(m0 + row)*K + k0 + c8, &As[(idx & ~63)*8]);
      gl_lds16(W + (size_t)(n0 + row)*K + k0 + c8, &Bs[(idx & ~63)*8]);
    }
    __syncthreads();
    bf16x8 af[4], bfr[4];
    #pragma unroll
    for (int i = 0; i < 4; i++){
      af[i]  = *(const bf16x8*)&As[(wm + i*16 + fr)*32 + fq*8];
      bfr[i] = *(const bf16x8*)&Bs[(wn + i*16 + fr)*32 + fq*8];
    }
    #pragma unroll
    for (int i = 0; i < 4; i++)
      #pragma unroll
      for (int j = 0; j < 4; j++)
        acc[i][j] = __builtin_amdgcn_mfma_f32_16x16x32_bf16(af[i], bfr[j], acc[i][j], 0,0,0);
  }
  #pragma unroll
  for (int i = 0; i < 4; i++){
    #pragma unroll
    for (int j = 0; j < 4; j++){
      int col = n0 + wn + j*16 + fr;
      #pragma unroll
      for (int r = 0; r < 4; r++){
        int row = m0 + wm + i*16 + fq*4 + r;
        float v = acc[i][j][r];
        if (EPI == EPI_F32){
          outf[(size_t)row*N + col] = v;
        } else {
          int b = row >> 11;   // row / T_
          float g = ada[b*SIX_D + g_off + col];
          outf[(size_t)row*N + col] = resid[(size_t)row*N + col] + g*(v + bias[col]);
        }
      }
    }
  }
}

// ---------------- fc1 dual (value+gate) with fused SwiGLU -> bf16 ----------------
__launch_bounds__(256)
__global__ void k_gemm_fc1(const unsigned short* __restrict__ A,
                           const unsigned short* __restrict__ W,   // (2*HID, D) bf16
                           const float* __restrict__ bias,          // (2*HID)
                           unsigned short* __restrict__ out){       // (B*T, HID) bf16
  __shared__ __align__(16) unsigned short As[128*32];
  __shared__ __align__(16) unsigned short Bv[128*32];
  __shared__ __align__(16) unsigned short Bg[128*32];
  const int K = D_;
  const int tid = threadIdx.x;
  const int wave = tid >> 6, lane = tid & 63;
  const int wm = (wave >> 1)*64, wn = (wave & 1)*64;
  const int m0 = blockIdx.y*128, n0 = blockIdx.x*128;
  const int fr = lane & 15, fq = lane >> 4;
  f32x4 accv[4][4] = {}, accg[4][4] = {};
  for (int k0 = 0; k0 < K; k0 += 32){
    __syncthreads();
    #pragma unroll
    for (int rr = 0; rr < 2; rr++){
      int idx = rr*256 + tid;
      int row = idx >> 2, c8 = (idx & 3)*8;
      gl_lds16(A + (size_t)(m0 + row)*K + k0 + c8,           &As[(idx & ~63)*8]);
      gl_lds16(W + (size_t)(n0 + row)*K + k0 + c8,           &Bv[(idx & ~63)*8]);
      gl_lds16(W + (size_t)(HID_ + n0 + row)*K + k0 + c8,    &Bg[(idx & ~63)*8]);
    }
    __syncthreads();
    bf16x8 af[4], bv[4], bg[4];
    #pragma unroll
    for (int i = 0; i < 4; i++){
      af[i] = *(const bf16x8*)&As[(wm + i*16 + fr)*32 + fq*8];
      bv[i] = *(const bf16x8*)&Bv[(wn + i*16 + fr)*32 + fq*8];
      bg[i] = *(const bf16x8*)&Bg[(wn + i*16 + fr)*32 + fq*8];
    }
    #pragma unroll
    for (int i = 0; i < 4; i++)
      #pragma unroll
      for (int j = 0; j < 4; j++){
        accv[i][j] = __builtin_amdgcn_mfma_f32_16x16x32_bf16(af[i], bv[j], accv[i][j], 0,0,0);
        accg[i][j] = __builtin_amdgcn_mfma_f32_16x16x32_bf16(af[i], bg[j], accg[i][j], 0,0,0);
      }
  }
  #pragma unroll
  for (int i = 0; i < 4; i++){
    #pragma unroll
    for (int j = 0; j < 4; j++){
      int col = n0 + wn + j*16 + fr;
      #pragma unroll
      for (int r = 0; r < 4; r++){
        int row = m0 + wm + i*16 + fq*4 + r;
        float vv = accv[i][j][r] + bias[col];
        float gg = accg[i][j][r] + bias[HID_ + col];
        float h = vv * (gg / (1.f + __expf(-gg)));
        out[(size_t)row*HID_ + col] = f2bf(h);
      }
    }
  }
}

// ---------------- qkv -> q,k with per-head rmsnorm + rope -> bf16 (B,NH,T,HD) ----------------
__global__ void k_qkv_post(const float* __restrict__ qkv,
                           const float* __restrict__ qw, const float* __restrict__ kw,
                           const int* __restrict__ wptr,
                           unsigned short* __restrict__ q, unsigned short* __restrict__ k){
  int idx = blockIdx.x;           // (b*T + t)*NH + h
  int h = idx & (NH_-1);
  int t = (idx >> 4) & (T_-1);
  int b = idx >> 15;
  int d = threadIdx.x;            // 0..63
  const float* base = qkv + (size_t)(b*T_ + t)*3072;
  float qv = base[h*64 + d];
  float kv = base[1024 + h*64 + d];
  float sq = qv*qv, sk = kv*kv;
  #pragma unroll
  for (int m = 32; m > 0; m >>= 1){ sq += __shfl_xor(sq, m, 64); sk += __shfl_xor(sk, m, 64); }
  qv *= rsqrtf(sq*(1.f/64.f) + 1e-6f) * qw[d];
  kv *= rsqrtf(sk*(1.f/64.f) + 1e-6f) * kw[d];
  int width = wptr[0];
  int yy = t / width, xx = t - yy*width;
  int coord = (d < 32) ? yy : xx;
  int fi = (d & 31) >> 1;
  float ifreq = __expf(-(float)fi * (9.210340371976184f/16.f));  // 10000^(-fi/16)
  float ang = (float)coord * ifreq;
  float cs = cosf(ang), sn = sinf(ang);
  float pq = __shfl_xor(qv, 1, 64);
  float pk = __shfl_xor(kv, 1, 64);
  float rq = (d & 1) ? pq : -pq;
  float rk = (d & 1) ? pk : -pk;
  qv = qv*cs + rq*sn;
  kv = kv*cs + rk*sn;
  size_t o = ((size_t)(b*NH_ + h)*T_ + t)*64 + d;
  q[o] = f2bf(qv); k[o] = f2bf(kv);
}

// ---------------- V transpose: qkv fp32 (b,t, 2048 + h*64+d) -> vt bf16 (b,h,d,t) ----------------
__global__ void k_vtrans(const float* __restrict__ qkv, unsigned short* __restrict__ vt){
  __shared__ __align__(16) unsigned short TT[64*64];  // [d][t], groups swizzled by g ^ ((d>>2)&7)
  int bh = blockIdx.y, t0 = blockIdx.x*64;
  int b = bh >> 4, h = bh & 15;
  int tid = threadIdx.x;
  #pragma unroll
  for (int it = 0; it < 4; it++){
    int i2 = it*256 + tid;
    int t = i2 >> 4, c4 = i2 & 15;
    float4 v = *(const float4*)(qkv + (size_t)(b*T_ + t0 + t)*3072 + 2048 + h*64 + c4*4);
    float vv[4] = {v.x, v.y, v.z, v.w};
    #pragma unroll
    for (int e = 0; e < 4; e++){
      int c = c4*4 + e;                        // channel d
      int gp = (t >> 3) ^ ((c >> 2) & 7);      // phys t-group
      TT[c*64 + gp*8 + (t & 7)] = f2bf(vv[e]);
    }
  }
  __syncthreads();
  #pragma unroll
  for (int it = 0; it < 2; it++){
    int i2 = it*256 + tid;
    int d = i2 >> 3, g = i2 & 7;
    int gp = g ^ ((d >> 2) & 7);
    *(uint4*)(vt + ((size_t)(bh*64 + d)*T_ + t0 + g*8)) = *(const uint4*)&TT[d*64 + gp*8];
  }
}

// ---------------- flash attention (fixed-shift softmax, K-split 2) ----------------
__launch_bounds__(256, 4)
__global__ void k_attn(const unsigned short* __restrict__ q,
                       const unsigned short* __restrict__ k,
                       const unsigned short* __restrict__ vt,
                       unsigned short* __restrict__ opart,   // [2][32][T][64] bf16
                       float* __restrict__ lpart){           // [2][32][T]
  __shared__ __align__(16) unsigned short Ks[64*64];
  __shared__ __align__(16) unsigned short Vs[64*64];
  __shared__ __align__(16) unsigned short Ps[4][32*64];
  const int tid = threadIdx.x;
  const int wave = tid >> 6, lane = tid & 63;
  const int fr = lane & 15, fq = lane >> 4;
  const int bh = blockIdx.y, q0 = blockIdx.x*128, ks = blockIdx.z;
  const unsigned short* kb = k  + (size_t)bh*T_*HD_;
  const unsigned short* vb = vt + (size_t)bh*HD_*T_;
  bf16x8 aq[2][2];
  {
    const unsigned short* qb = q + (size_t)bh*T_*HD_;
    #pragma unroll
    for (int i = 0; i < 2; i++)
      #pragma unroll
      for (int kk = 0; kk < 2; kk++)
        aq[i][kk] = *(const bf16x8*)(qb + (size_t)(q0 + wave*32 + i*16 + fr)*HD_ + kk*32 + fq*8);
  }
  f32x4 o[2][4] = {};
  float lsum[2][4] = {};
  const int kbeg = ks*1024, kend = kbeg + 1024;
  for (int kt = kbeg; kt < kend; kt += 64){
    __syncthreads();
    #pragma unroll
    for (int it = 0; it < 2; it++){
      int i2 = it*256 + tid;
      int row = i2 >> 3, g = i2 & 7, gp = g ^ (row & 7);
      ((uint4*)Ks)[row*8 + gp] = ((const uint4*)kb)[(kt + row)*8 + g];
      ((uint4*)Vs)[row*8 + gp] = ((const uint4*)vb)[row*256 + (kt >> 3) + g];
    }
    __syncthreads();
    // S = Q K^T
    f32x4 s[2][4] = {};
    #pragma unroll
    for (int kk = 0; kk < 2; kk++){
      bf16x8 bk[4];
      #pragma unroll
      for (int j = 0; j < 4; j++)
        bk[j] = *(const bf16x8*)&Ks[(j*16 + fr)*64 + ((kk*4 + fq) ^ (fr & 7))*8];
      #pragma unroll
      for (int i = 0; i < 2; i++)
        #pragma unroll
        for (int j = 0; j < 4; j++)
          s[i][j] = __builtin_amdgcn_mfma_f32_16x16x32_bf16(aq[i][kk], bk[j], s[i][j], 0,0,0);
    }
    // fixed-shift softmax: p = exp(clamp(s/8)), no cross-lane reduce in loop
    unsigned short* Pw = Ps[wave];
    #pragma unroll
    for (int i = 0; i < 2; i++)
      #pragma unroll
      for (int j = 0; j < 4; j++)
        #pragma unroll
        for (int r = 0; r < 4; r++){
          float sv = s[i][j][r]*0.125f;
          sv = fminf(fmaxf(sv, -30.f), 30.f);
          float p = __expf(sv);
          lsum[i][r] += p;
          int row = i*16 + fq*4 + r;
          int gp = (j*2 + (fr >> 3)) ^ (row & 7);
          Pw[row*64 + gp*8 + (fr & 7)] = f2bf(p);
        }
    // O += P V
    #pragma unroll
    for (int kk = 0; kk < 2; kk++){
      bf16x8 ap[2], bv[4];
      #pragma unroll
      for (int i = 0; i < 2; i++)
        ap[i] = *(const bf16x8*)&Pw[(i*16 + fr)*64 + ((kk*4 + fq) ^ (fr & 7))*8];
      #pragma unroll
      for (int dn = 0; dn < 4; dn++)
        bv[dn] = *(const bf16x8*)&Vs[(dn*16 + fr)*64 + ((kk*4 + fq) ^ (fr & 7))*8];
      #pragma unroll
      for (int i = 0; i < 2; i++)
        #pragma unroll
        for (int dn = 0; dn < 4; dn++)
          o[i][dn] = __builtin_amdgcn_mfma_f32_16x16x32_bf16(ap[i], bv[dn], o[i][dn], 0,0,0);
    }
  }
  // epilogue: row-sum reduce (once), write bf16 o-partials + fp32 l-partials
  #pragma unroll
  for (int i = 0; i < 2; i++)
    #pragma unroll
    for (int r = 0; r < 4; r++){
      float l = lsum[i][r];
      #pragma unroll
      for (int m = 1; m < 16; m <<= 1) l += __shfl_xor(l, m, 64);
      lsum[i][r] = l;
    }
  unsigned short* ob = opart + ((size_t)(ks*32 + bh)*T_ + q0)*HD_;
  float* lb = lpart + (size_t)(ks*32 + bh)*T_ + q0;
  #pragma unroll
  for (int i = 0; i < 2; i++)
    #pragma unroll
    for (int r = 0; r < 4; r++){
      int row = wave*32 + i*16 + fq*4 + r;
      #pragma unroll
      for (int dn = 0; dn < 4; dn++)
        ob[(size_t)row*HD_ + dn*16 + fr] = f2bf(o[i][dn][r]);
      if (fr == 0) lb[row] = lsum[i][r];
    }
}

// ---------------- combine K-split partials -> attn_o (B,T,D) bf16 ----------------
__global__ void k_attn_comb(const unsigned short* __restrict__ opart,
                            const float* __restrict__ lpart,
                            unsigned short* __restrict__ out){
  int i = blockIdx.x*256 + threadIdx.x;     // over 32*2048*16
  int bhq = i >> 4, c = i & 15;
  ushort4 a  = ((const ushort4*)opart)[bhq*16 + c];
  ushort4 b4 = ((const ushort4*)(opart + 32ull*T_*HD_))[bhq*16 + c];
  float inv = 1.f / (lpart[bhq] + lpart[32*T_ + bhq]);
  ushort4 o;
  o.x = f2bf((bf2f(a.x) + bf2f(b4.x))*inv);
  o.y = f2bf((bf2f(a.y) + bf2f(b4.y))*inv);
  o.z = f2bf((bf2f(a.z) + bf2f(b4.z))*inv);
  o.w = f2bf((bf2f(a.w) + bf2f(b4.w))*inv);
  int bh = bhq >> 11, t = bhq & (T_-1);
  int b = bh >> 4, h = bh & 15;
  ((ushort4*)out)[(size_t)(b*T_ + t)*(D_/4) + h*16 + c] = o;
}

extern "C" void kernel_launch(void* const* d_in, const int* in_sizes, int n_in,
                              void* d_out, int out_size, void* d_ws, size_t ws_size,
                              hipStream_t stream){
  const float* x      = (const float*)d_in[0];
  const float* cond   = (const float*)d_in[1];
  const float* norm1w = (const float*)d_in[2];
  const float* qkv_w  = (const float*)d_in[3];
  const float* q_nw   = (const float*)d_in[4];
  const float* k_nw   = (const float*)d_in[5];
  const float* proj_w = (const float*)d_in[6];
  const float* proj_b = (const float*)d_in[7];
  const float* norm2w = (const float*)d_in[8];
  const float* fc1_w  = (const float*)d_in[9];
  const float* fc1_b  = (const float*)d_in[10];
  const float* fc2_w  = (const float*)d_in[11];
  const float* fc2_b  = (const float*)d_in[12];
  const float* ada_w  = (const float*)d_in[13];
  const float* ada_b  = (const float*)d_in[14];
  const int*   wptr   = (const int*)d_in[16];
  float* out = (float*)d_out;

  char* ws = (char*)d_ws;
  size_t off = 0;
  auto alloc = [&](size_t bytes)->void*{
    void* p = ws + off; off += (bytes + 255) & ~(size_t)255; return p;
  };
  unsigned short* w_qkv  = (unsigned short*)alloc(3072ull*1024*2);
  unsigned short* w_proj = (unsigned short*)alloc(1024ull*1024*2);
  unsigned short* w_fc1  = (unsigned short*)alloc(8192ull*1024*2);
  unsigned short* w_fc2  = (unsigned short*)alloc(1024ull*4096*2);
  float* ada             = (float*)alloc((size_t)B_*SIX_D*4);
  unsigned short* h1     = (unsigned short*)alloc(4096ull*1024*2);
  // region R: qkv_out (fp32, 50.3 MB) lives until k_vtrans; afterwards reused
  char* R                = (char*)alloc(4096ull*3072*4);
  float* qkv_out         = (float*)R;
  unsigned short* opart  = (unsigned short*)R;                         // 16.78 MB
  float* lpart           = (float*)(R + 2ull*32*T_*HD_*2);             // 0.5 MB
  unsigned short* attn_o = (unsigned short*)(R + 2ull*32*T_*HD_*2 + 2ull*32*T_*4); // 8.39 MB
  float* x1              = (float*)(R + 2ull*32*T_*HD_*2 + 2ull*32*T_*4 + (size_t)B_*T_*D_*2);
  unsigned short* qb     = (unsigned short*)alloc(32ull*2048*64*2);
  unsigned short* kb     = (unsigned short*)alloc(32ull*2048*64*2);
  unsigned short* vt     = (unsigned short*)alloc(32ull*64*2048*2);
  unsigned short* mlp    = (unsigned short*)alloc(4096ull*4096*2);
  (void)ws_size; (void)in_sizes; (void)n_in; (void)out_size;

  // weights -> bf16
  k_conv_bf16<<<3072, 256, 0, stream>>>(qkv_w,  w_qkv,  3072*1024/4);
  k_conv_bf16<<<1024, 256, 0, stream>>>(proj_w, w_proj, 1024*1024/4);
  k_conv_bf16<<<8192, 256, 0, stream>>>(fc1_w,  w_fc1,  8192*1024/4);
  k_conv_bf16<<<4096, 256, 0, stream>>>(fc2_w,  w_fc2,  4096*1024/4);

  k_ada<<<dim3(SIX_D/256, B_), 256, 0, stream>>>(cond, ada_w, ada_b, ada);
  k_norm_mod<<<B_*T_, 256, 0, stream>>>(x, norm1w, ada, 0, D_, h1);
  k_gemm_bt<EPI_F32><<<dim3(3072/128, 4096/128), 256, 0, stream>>>(
      h1, w_qkv, B_*T_, 3*D_, D_, qkv_out, nullptr, nullptr, 0, nullptr);
  k_qkv_post<<<B_*T_*NH_, 64, 0, stream>>>(qkv_out, q_nw, k_nw, wptr, qb, kb);
  k_vtrans<<<dim3(T_/64, 32), 256, 0, stream>>>(qkv_out, vt);
  k_attn<<<dim3(T_/128, 32, 2), 256, 0, stream>>>(qb, kb, vt, opart, lpart);
  k_attn_comb<<<32*T_*16/256, 256, 0, stream>>>(opart, lpart, attn_o);
  k_gemm_bt<EPI_RESID><<<dim3(1024/128, 4096/128), 256, 0, stream>>>(
      attn_o, w_proj, B_*T_, D_, D_, x1, x, ada, 2*D_, proj_b);
  k_norm_mod<<<B_*T_, 256, 0, stream>>>(x1, norm2w, ada, 3*D_, 4*D_, h1);
  k_gemm_fc1<<<dim3(4096/128, 4096/128), 256, 0, stream>>>(h1, w_fc1, fc1_b, mlp);
  k_gemm_bt<EPI_RESID><<<dim3(1024/128, 4096/128), 256, 0, stream>>>(
      mlp, w_fc2, B_*T_, D_, HID_, out, x1, ada, 5*D_, fc2_b);
}

// Round 4
// 617.750 us; speedup vs baseline: 1.2766x; 1.1362x over previous
//
#include <hip/hip_runtime.h>
#include <hip/hip_bf16.h>

#define B_   2
#define T_   2048
#define D_   1024
#define NH_  16
#define HD_  64
#define HID_ 4096
#define CD_  1024
#define SIX_D (6*D_)

typedef __bf16 bf16x8 __attribute__((ext_vector_type(8)));
typedef float  f32x4  __attribute__((ext_vector_type(4)));

__device__ __forceinline__ unsigned short f2bf(float f){
  union { float f; unsigned u; } v; v.f = f;
  unsigned r = v.u + 0x7FFFu + ((v.u >> 16) & 1u);
  return (unsigned short)(r >> 16);
}
__device__ __forceinline__ float bf2f(unsigned short u){
  union { unsigned x; float f; } v; v.x = ((unsigned)u) << 16; return v.f;
}

__device__ __forceinline__ void gl_lds16(const void* g, void* l){
  __builtin_amdgcn_global_load_lds(
      (__attribute__((address_space(1))) void*)const_cast<void*>(g),
      (__attribute__((address_space(3))) void*)l, 16, 0, 0);
}

// ---------------- all weights fp32 -> bf16, single launch ----------------
// Each block converts 256 float4 = 1024 elements.
// Block counts: qkv 3072*1024/1024=3072 | proj 1024*1024/1024=1024
//               fc1 8192*1024/1024=8192 | fc2 1024*4096/1024=4096  => 16384 total
__global__ void k_conv_all(const float* __restrict__ s0, const float* __restrict__ s1,
                           const float* __restrict__ s2, const float* __restrict__ s3,
                           unsigned short* __restrict__ d0, unsigned short* __restrict__ d1,
                           unsigned short* __restrict__ d2, unsigned short* __restrict__ d3){
  int bid = blockIdx.x;
  const float* s; unsigned short* d; int base;
  if (bid < 3072)      { s = s0; d = d0; base = bid; }
  else if (bid < 4096) { s = s1; d = d1; base = bid - 3072; }
  else if (bid < 12288){ s = s2; d = d2; base = bid - 4096; }
  else                 { s = s3; d = d3; base = bid - 12288; }
  int i = base*256 + threadIdx.x;
  float4 v = reinterpret_cast<const float4*>(s)[i];
  ushort4 o;
  o.x = f2bf(v.x); o.y = f2bf(v.y); o.z = f2bf(v.z); o.w = f2bf(v.w);
  reinterpret_cast<ushort4*>(d)[i] = o;
}

// ---------------- ada = silu(cond) @ ada_w.T + ada_b ----------------
__global__ void k_ada(const float* __restrict__ cond, const float* __restrict__ ada_w,
                      const float* __restrict__ ada_b, float* __restrict__ ada){
  __shared__ float sc[CD_];
  int b = blockIdx.y;
  int tid = threadIdx.x;
  for (int i = tid; i < CD_; i += 256){
    float c = cond[b*CD_ + i];
    sc[i] = c / (1.f + __expf(-c));
  }
  __syncthreads();
  int col = blockIdx.x*256 + tid;
  const float* wr = ada_w + (size_t)col*CD_;
  float acc = 0.f;
  #pragma unroll 4
  for (int k = 0; k < CD_; k++) acc += sc[k]*wr[k];
  ada[b*SIX_D + col] = acc + ada_b[col];
}

// ---------------- rmsnorm + modulate -> bf16 ----------------
__global__ void k_norm_mod(const float* __restrict__ x, const float* __restrict__ w,
                           const float* __restrict__ ada, int sh_off, int sc_off,
                           unsigned short* __restrict__ out){
  int row = blockIdx.x;           // b*T + t
  int b = row >> 11;              // / T_
  int tid = threadIdx.x;
  float4 xv = reinterpret_cast<const float4*>(x + (size_t)row*D_)[tid];
  float ss = xv.x*xv.x + xv.y*xv.y + xv.z*xv.z + xv.w*xv.w;
  #pragma unroll
  for (int m = 32; m > 0; m >>= 1) ss += __shfl_xor(ss, m, 64);
  __shared__ float red[4];
  int wave = tid >> 6;
  if ((tid & 63) == 0) red[wave] = ss;
  __syncthreads();
  float tot = red[0]+red[1]+red[2]+red[3];
  float rn = rsqrtf(tot * (1.f/(float)D_) + 1e-6f);
  float4 wv  = reinterpret_cast<const float4*>(w)[tid];
  float4 scv = reinterpret_cast<const float4*>(ada + b*SIX_D + sc_off)[tid];
  float4 shv = reinterpret_cast<const float4*>(ada + b*SIX_D + sh_off)[tid];
  ushort4 o;
  o.x = f2bf(xv.x*rn*wv.x*(1.f+scv.x)+shv.x);
  o.y = f2bf(xv.y*rn*wv.y*(1.f+scv.y)+shv.y);
  o.z = f2bf(xv.z*rn*wv.z*(1.f+scv.z)+shv.z);
  o.w = f2bf(xv.w*rn*wv.w*(1.f+scv.w)+shv.w);
  reinterpret_cast<ushort4*>(out + (size_t)row*D_)[tid] = o;
}

// ---------------- 128x128 GEMM: C = A(MxK) * W(NxK)^T ----------------
enum { EPI_F32 = 0, EPI_RESID = 1, EPI_BF16 = 2 };

template<int EPI>
__launch_bounds__(256)
__global__ void k_gemm_bt(const unsigned short* __restrict__ A,
                          const unsigned short* __restrict__ W,
                          int M, int N, int K,
                          void* __restrict__ outp,
                          const float* __restrict__ resid,
                          const float* __restrict__ ada, int g_off,
                          const float* __restrict__ bias){
  __shared__ __align__(16) unsigned short As[128*32];
  __shared__ __align__(16) unsigned short Bs[128*32];
  const int tid = threadIdx.x;
  const int wave = tid >> 6, lane = tid & 63;
  const int wm = (wave >> 1)*64, wn = (wave & 1)*64;
  const int m0 = blockIdx.y*128, n0 = blockIdx.x*128;
  const int fr = lane & 15, fq = lane >> 4;
  f32x4 acc[4][4] = {};
  for (int k0 = 0; k0 < K; k0 += 32){
    __syncthreads();
    #pragma unroll
    for (int rr = 0; rr < 2; rr++){
      int idx = rr*256 + tid;
      int row = idx >> 2, c8 = (idx & 3)*8;
      gl_lds16(A + (size_t)(m0 + row)*K + k0 + c8, &As[(idx & ~63)*8]);
      gl_lds16(W + (size_t)(n0 + row)*K + k0 + c8, &Bs[(idx & ~63)*8]);
    }
    __syncthreads();
    bf16x8 af[4], bfr[4];
    #pragma unroll
    for (int i = 0; i < 4; i++){
      af[i]  = *(const bf16x8*)&As[(wm + i*16 + fr)*32 + fq*8];
      bfr[i] = *(const bf16x8*)&Bs[(wn + i*16 + fr)*32 + fq*8];
    }
    #pragma unroll
    for (int i = 0; i < 4; i++)
      #pragma unroll
      for (int j = 0; j < 4; j++)
        acc[i][j] = __builtin_amdgcn_mfma_f32_16x16x32_bf16(af[i], bfr[j], acc[i][j], 0,0,0);
  }
  #pragma unroll
  for (int i = 0; i < 4; i++){
    #pragma unroll
    for (int j = 0; j < 4; j++){
      int col = n0 + wn + j*16 + fr;
      #pragma unroll
      for (int r = 0; r < 4; r++){
        int row = m0 + wm + i*16 + fq*4 + r;
        float v = acc[i][j][r];
        if (EPI == EPI_F32){
          ((float*)outp)[(size_t)row*N + col] = v;
        } else if (EPI == EPI_BF16){
          ((unsigned short*)outp)[(size_t)row*N + col] = f2bf(v);
        } else {
          int b = row >> 11;
          float g = ada[b*SIX_D + g_off + col];
          ((float*)outp)[(size_t)row*N + col] = resid[(size_t)row*N + col] + g*(v + bias[col]);
        }
      }
    }
  }
}

// ---------------- 64x128 GEMM (for N=1024 shapes: proj, fc2) ----------------
template<int EPI>
__launch_bounds__(256)
__global__ void k_gemm_bt64(const unsigned short* __restrict__ A,
                            const unsigned short* __restrict__ W,
                            int M, int N, int K,
                            void* __restrict__ outp,
                            const float* __restrict__ resid,
                            const float* __restrict__ ada, int g_off,
                            const float* __restrict__ bias){
  __shared__ __align__(16) unsigned short As[64*32];
  __shared__ __align__(16) unsigned short Bs[128*32];
  const int tid = threadIdx.x;
  const int wave = tid >> 6, lane = tid & 63;
  const int wm = (wave >> 1)*32, wn = (wave & 1)*64;
  const int m0 = blockIdx.y*64, n0 = blockIdx.x*128;
  const int fr = lane & 15, fq = lane >> 4;
  f32x4 acc[2][4] = {};
  for (int k0 = 0; k0 < K; k0 += 32){
    __syncthreads();
    {
      int row = tid >> 2, c8 = (tid & 3)*8;
      gl_lds16(A + (size_t)(m0 + row)*K + k0 + c8, &As[(tid & ~63)*8]);
    }
    #pragma unroll
    for (int rr = 0; rr < 2; rr++){
      int idx = rr*256 + tid;
      int row = idx >> 2, c8 = (idx & 3)*8;
      gl_lds16(W + (size_t)(n0 + row)*K + k0 + c8, &Bs[(idx & ~63)*8]);
    }
    __syncthreads();
    bf16x8 af[2], bfr[4];
    #pragma unroll
    for (int i = 0; i < 2; i++)
      af[i]  = *(const bf16x8*)&As[(wm + i*16 + fr)*32 + fq*8];
    #pragma unroll
    for (int j = 0; j < 4; j++)
      bfr[j] = *(const bf16x8*)&Bs[(wn + j*16 + fr)*32 + fq*8];
    #pragma unroll
    for (int i = 0; i < 2; i++)
      #pragma unroll
      for (int j = 0; j < 4; j++)
        acc[i][j] = __builtin_amdgcn_mfma_f32_16x16x32_bf16(af[i], bfr[j], acc[i][j], 0,0,0);
  }
  #pragma unroll
  for (int i = 0; i < 2; i++){
    #pragma unroll
    for (int j = 0; j < 4; j++){
      int col = n0 + wn + j*16 + fr;
      #pragma unroll
      for (int r = 0; r < 4; r++){
        int row = m0 + wm + i*16 + fq*4 + r;
        float v = acc[i][j][r];
        if (EPI == EPI_F32){
          ((float*)outp)[(size_t)row*N + col] = v;
        } else if (EPI == EPI_BF16){
          ((unsigned short*)outp)[(size_t)row*N + col] = f2bf(v);
        } else {
          int b = row >> 11;
          float g = ada[b*SIX_D + g_off + col];
          ((float*)outp)[(size_t)row*N + col] = resid[(size_t)row*N + col] + g*(v + bias[col]);
        }
      }
    }
  }
}

// ---------------- fc1 dual 128x(64+64) with fused SwiGLU -> bf16 ----------------
__launch_bounds__(256)
__global__ void k_gemm_fc1(const unsigned short* __restrict__ A,
                           const unsigned short* __restrict__ W,   // (2*HID, D) bf16
                           const float* __restrict__ bias,          // (2*HID)
                           unsigned short* __restrict__ out){       // (B*T, HID) bf16
  __shared__ __align__(16) unsigned short As[128*32];
  __shared__ __align__(16) unsigned short Bv[64*32];
  __shared__ __align__(16) unsigned short Bg[64*32];
  const int K = D_;
  const int tid = threadIdx.x;
  const int wave = tid >> 6, lane = tid & 63;
  const int wm = (wave >> 1)*64, wn = (wave & 1)*32;
  const int m0 = blockIdx.y*128, n0 = blockIdx.x*64;
  const int fr = lane & 15, fq = lane >> 4;
  f32x4 accv[4][2] = {}, accg[4][2] = {};
  for (int k0 = 0; k0 < K; k0 += 32){
    __syncthreads();
    #pragma unroll
    for (int rr = 0; rr < 2; rr++){
      int idx = rr*256 + tid;
      int row = idx >> 2, c8 = (idx & 3)*8;
      gl_lds16(A + (size_t)(m0 + row)*K + k0 + c8, &As[(idx & ~63)*8]);
    }
    {
      int row = tid >> 2, c8 = (tid & 3)*8;
      gl_lds16(W + (size_t)(n0 + row)*K + k0 + c8,        &Bv[(tid & ~63)*8]);
      gl_lds16(W + (size_t)(HID_ + n0 + row)*K + k0 + c8, &Bg[(tid & ~63)*8]);
    }
    __syncthreads();
    bf16x8 af[4], bv[2], bg[2];
    #pragma unroll
    for (int i = 0; i < 4; i++)
      af[i] = *(const bf16x8*)&As[(wm + i*16 + fr)*32 + fq*8];
    #pragma unroll
    for (int j = 0; j < 2; j++){
      bv[j] = *(const bf16x8*)&Bv[(wn + j*16 + fr)*32 + fq*8];
      bg[j] = *(const bf16x8*)&Bg[(wn + j*16 + fr)*32 + fq*8];
    }
    #pragma unroll
    for (int i = 0; i < 4; i++)
      #pragma unroll
      for (int j = 0; j < 2; j++){
        accv[i][j] = __builtin_amdgcn_mfma_f32_16x16x32_bf16(af[i], bv[j], accv[i][j], 0,0,0);
        accg[i][j] = __builtin_amdgcn_mfma_f32_16x16x32_bf16(af[i], bg[j], accg[i][j], 0,0,0);
      }
  }
  #pragma unroll
  for (int i = 0; i < 4; i++){
    #pragma unroll
    for (int j = 0; j < 2; j++){
      int col = n0 + wn + j*16 + fr;
      #pragma unroll
      for (int r = 0; r < 4; r++){
        int row = m0 + wm + i*16 + fq*4 + r;
        float vv = accv[i][j][r] + bias[col];
        float gg = accg[i][j][r] + bias[HID_ + col];
        float h = vv * (gg / (1.f + __expf(-gg)));
        out[(size_t)row*HID_ + col] = f2bf(h);
      }
    }
  }
}

// ---------------- qkv(bf16) -> q,k with per-head rmsnorm + rope -> bf16 (B,NH,T,HD) ----------------
__global__ void k_qkv_post(const unsigned short* __restrict__ qkv,
                           const float* __restrict__ qw, const float* __restrict__ kw,
                           const int* __restrict__ wptr,
                           unsigned short* __restrict__ q, unsigned short* __restrict__ k){
  int idx = blockIdx.x;           // (b*T + t)*NH + h
  int h = idx & (NH_-1);
  int t = (idx >> 4) & (T_-1);
  int b = idx >> 15;
  int d = threadIdx.x;            // 0..63
  const unsigned short* base = qkv + (size_t)(b*T_ + t)*3072;
  float qv = bf2f(base[h*64 + d]);
  float kv = bf2f(base[1024 + h*64 + d]);
  float sq = qv*qv, sk = kv*kv;
  #pragma unroll
  for (int m = 32; m > 0; m >>= 1){ sq += __shfl_xor(sq, m, 64); sk += __shfl_xor(sk, m, 64); }
  qv *= rsqrtf(sq*(1.f/64.f) + 1e-6f) * qw[d];
  kv *= rsqrtf(sk*(1.f/64.f) + 1e-6f) * kw[d];
  int width = wptr[0];
  int yy = t / width, xx = t - yy*width;
  int coord = (d < 32) ? yy : xx;
  int fi = (d & 31) >> 1;
  float ifreq = __expf(-(float)fi * (9.210340371976184f/16.f));  // 10000^(-fi/16)
  float ang = (float)coord * ifreq;
  float cs = cosf(ang), sn = sinf(ang);
  float pq = __shfl_xor(qv, 1, 64);
  float pk = __shfl_xor(kv, 1, 64);
  float rq = (d & 1) ? pq : -pq;
  float rk = (d & 1) ? pk : -pk;
  qv = qv*cs + rq*sn;
  kv = kv*cs + rk*sn;
  size_t o = ((size_t)(b*NH_ + h)*T_ + t)*64 + d;
  q[o] = f2bf(qv); k[o] = f2bf(kv);
}

// ---------------- V transpose: qkv bf16 (b,t, 2048 + h*64+d) -> vt bf16 (b,h,d,t) ----------------
__global__ void k_vtrans(const unsigned short* __restrict__ qkv, unsigned short* __restrict__ vt){
  __shared__ __align__(16) unsigned short TT[64*64];  // [d][t], groups swizzled
  int bh = blockIdx.y, t0 = blockIdx.x*64;
  int b = bh >> 4, h = bh & 15;
  int tid = threadIdx.x;
  #pragma unroll
  for (int it = 0; it < 2; it++){
    int i2 = it*256 + tid;
    int t = i2 >> 3, c8 = (i2 & 7)*8;
    union { uint4 v; unsigned short u[8]; } ld;
    ld.v = *(const uint4*)(qkv + (size_t)(b*T_ + t0 + t)*3072 + 2048 + h*64 + c8);
    #pragma unroll
    for (int e = 0; e < 8; e++){
      int c = c8 + e;
      int gp = (t >> 3) ^ ((c >> 2) & 7);
      TT[c*64 + gp*8 + (t & 7)] = ld.u[e];
    }
  }
  __syncthreads();
  #pragma unroll
  for (int it = 0; it < 2; it++){
    int i2 = it*256 + tid;
    int d = i2 >> 3, g = i2 & 7;
    int gp = g ^ ((d >> 2) & 7);
    *(uint4*)(vt + ((size_t)(bh*64 + d)*T_ + t0 + g*8)) = *(const uint4*)&TT[d*64 + gp*8];
  }
}

// ---------------- flash attention (fixed-shift softmax, K-split 2) ----------------
__launch_bounds__(256, 4)
__global__ void k_attn(const unsigned short* __restrict__ q,
                       const unsigned short* __restrict__ k,
                       const unsigned short* __restrict__ vt,
                       unsigned short* __restrict__ opart,   // [2][32][T][64] bf16
                       float* __restrict__ lpart){           // [2][32][T]
  __shared__ __align__(16) unsigned short Ks[64*64];
  __shared__ __align__(16) unsigned short Vs[64*64];
  __shared__ __align__(16) unsigned short Ps[4][32*64];
  const int tid = threadIdx.x;
  const int wave = tid >> 6, lane = tid & 63;
  const int fr = lane & 15, fq = lane >> 4;
  const int bh = blockIdx.y, q0 = blockIdx.x*128, ks = blockIdx.z;
  const unsigned short* kb = k  + (size_t)bh*T_*HD_;
  const unsigned short* vb = vt + (size_t)bh*HD_*T_;
  bf16x8 aq[2][2];
  {
    const unsigned short* qb = q + (size_t)bh*T_*HD_;
    #pragma unroll
    for (int i = 0; i < 2; i++)
      #pragma unroll
      for (int kk = 0; kk < 2; kk++)
        aq[i][kk] = *(const bf16x8*)(qb + (size_t)(q0 + wave*32 + i*16 + fr)*HD_ + kk*32 + fq*8);
  }
  f32x4 o[2][4] = {};
  float lsum[2][4] = {};
  const int kbeg = ks*1024, kend = kbeg + 1024;
  for (int kt = kbeg; kt < kend; kt += 64){
    __syncthreads();
    #pragma unroll
    for (int it = 0; it < 2; it++){
      int i2 = it*256 + tid;
      int row = i2 >> 3, g = i2 & 7, gp = g ^ (row & 7);
      ((uint4*)Ks)[row*8 + gp] = ((const uint4*)kb)[(kt + row)*8 + g];
      ((uint4*)Vs)[row*8 + gp] = ((const uint4*)vb)[row*256 + (kt >> 3) + g];
    }
    __syncthreads();
    // S = Q K^T
    f32x4 s[2][4] = {};
    #pragma unroll
    for (int kk = 0; kk < 2; kk++){
      bf16x8 bk[4];
      #pragma unroll
      for (int j = 0; j < 4; j++)
        bk[j] = *(const bf16x8*)&Ks[(j*16 + fr)*64 + ((kk*4 + fq) ^ (fr & 7))*8];
      #pragma unroll
      for (int i = 0; i < 2; i++)
        #pragma unroll
        for (int j = 0; j < 4; j++)
          s[i][j] = __builtin_amdgcn_mfma_f32_16x16x32_bf16(aq[i][kk], bk[j], s[i][j], 0,0,0);
    }
    // fixed-shift softmax: p = exp(clamp(s/8)), no cross-lane reduce in loop
    unsigned short* Pw = Ps[wave];
    #pragma unroll
    for (int i = 0; i < 2; i++)
      #pragma unroll
      for (int j = 0; j < 4; j++)
        #pragma unroll
        for (int r = 0; r < 4; r++){
          float sv = s[i][j][r]*0.125f;
          sv = fminf(fmaxf(sv, -30.f), 30.f);
          float p = __expf(sv);
          lsum[i][r] += p;
          int row = i*16 + fq*4 + r;
          int gp = (j*2 + (fr >> 3)) ^ (row & 7);
          Pw[row*64 + gp*8 + (fr & 7)] = f2bf(p);
        }
    // O += P V
    #pragma unroll
    for (int kk = 0; kk < 2; kk++){
      bf16x8 ap[2], bv[4];
      #pragma unroll
      for (int i = 0; i < 2; i++)
        ap[i] = *(const bf16x8*)&Pw[(i*16 + fr)*64 + ((kk*4 + fq) ^ (fr & 7))*8];
      #pragma unroll
      for (int dn = 0; dn < 4; dn++)
        bv[dn] = *(const bf16x8*)&Vs[(dn*16 + fr)*64 + ((kk*4 + fq) ^ (fr & 7))*8];
      #pragma unroll
      for (int i = 0; i < 2; i++)
        #pragma unroll
        for (int dn = 0; dn < 4; dn++)
          o[i][dn] = __builtin_amdgcn_mfma_f32_16x16x32_bf16(ap[i], bv[dn], o[i][dn], 0,0,0);
    }
  }
  // epilogue
  #pragma unroll
  for (int i = 0; i < 2; i++)
    #pragma unroll
    for (int r = 0; r < 4; r++){
      float l = lsum[i][r];
      #pragma unroll
      for (int m = 1; m < 16; m <<= 1) l += __shfl_xor(l, m, 64);
      lsum[i][r] = l;
    }
  unsigned short* ob = opart + ((size_t)(ks*32 + bh)*T_ + q0)*HD_;
  float* lb = lpart + (size_t)(ks*32 + bh)*T_ + q0;
  #pragma unroll
  for (int i = 0; i < 2; i++)
    #pragma unroll
    for (int r = 0; r < 4; r++){
      int row = wave*32 + i*16 + fq*4 + r;
      #pragma unroll
      for (int dn = 0; dn < 4; dn++)
        ob[(size_t)row*HD_ + dn*16 + fr] = f2bf(o[i][dn][r]);
      if (fr == 0) lb[row] = lsum[i][r];
    }
}

// ---------------- combine K-split partials -> attn_o (B,T,D) bf16 ----------------
__global__ void k_attn_comb(const unsigned short* __restrict__ opart,
                            const float* __restrict__ lpart,
                            unsigned short* __restrict__ out){
  int i = blockIdx.x*256 + threadIdx.x;     // over 32*2048*16
  int bhq = i >> 4, c = i & 15;
  ushort4 a  = ((const ushort4*)opart)[bhq*16 + c];
  ushort4 b4 = ((const ushort4*)(opart + 32ull*T_*HD_))[bhq*16 + c];
  float inv = 1.f / (lpart[bhq] + lpart[32*T_ + bhq]);
  ushort4 o;
  o.x = f2bf((bf2f(a.x) + bf2f(b4.x))*inv);
  o.y = f2bf((bf2f(a.y) + bf2f(b4.y))*inv);
  o.z = f2bf((bf2f(a.z) + bf2f(b4.z))*inv);
  o.w = f2bf((bf2f(a.w) + bf2f(b4.w))*inv);
  int bh = bhq >> 11, t = bhq & (T_-1);
  int b = bh >> 4, h = bh & 15;
  ((ushort4*)out)[(size_t)(b*T_ + t)*(D_/4) + h*16 + c] = o;
}

extern "C" void kernel_launch(void* const* d_in, const int* in_sizes, int n_in,
                              void* d_out, int out_size, void* d_ws, size_t ws_size,
                              hipStream_t stream){
  const float* x      = (const float*)d_in[0];
  const float* cond   = (const float*)d_in[1];
  const float* norm1w = (const float*)d_in[2];
  const float* qkv_w  = (const float*)d_in[3];
  const float* q_nw   = (const float*)d_in[4];
  const float* k_nw   = (const float*)d_in[5];
  const float* proj_w = (const float*)d_in[6];
  const float* proj_b = (const float*)d_in[7];
  const float* norm2w = (const float*)d_in[8];
  const float* fc1_w  = (const float*)d_in[9];
  const float* fc1_b  = (const float*)d_in[10];
  const float* fc2_w  = (const float*)d_in[11];
  const float* fc2_b  = (const float*)d_in[12];
  const float* ada_w  = (const float*)d_in[13];
  const float* ada_b  = (const float*)d_in[14];
  const int*   wptr   = (const int*)d_in[16];
  float* out = (float*)d_out;

  char* ws = (char*)d_ws;
  size_t off = 0;
  auto alloc = [&](size_t bytes)->void*{
    void* p = ws + off; off += (bytes + 255) & ~(size_t)255; return p;
  };
  unsigned short* w_qkv  = (unsigned short*)alloc(3072ull*1024*2);
  unsigned short* w_proj = (unsigned short*)alloc(1024ull*1024*2);
  unsigned short* w_fc1  = (unsigned short*)alloc(8192ull*1024*2);
  unsigned short* w_fc2  = (unsigned short*)alloc(1024ull*4096*2);
  float* ada             = (float*)alloc((size_t)B_*SIX_D*4);
  unsigned short* h1     = (unsigned short*)alloc(4096ull*1024*2);
  // region R: qkv_out bf16 (25 MB) lives until k_vtrans; afterwards reused
  char* R                = (char*)alloc(4096ull*3072*4);
  unsigned short* qkv_out= (unsigned short*)R;
  unsigned short* opart  = (unsigned short*)R;                         // 16.78 MB
  float* lpart           = (float*)(R + 2ull*32*T_*HD_*2);             // 0.5 MB
  unsigned short* attn_o = (unsigned short*)(R + 2ull*32*T_*HD_*2 + 2ull*32*T_*4); // 8.39 MB
  float* x1              = (float*)(R + 2ull*32*T_*HD_*2 + 2ull*32*T_*4 + (size_t)B_*T_*D_*2);
  unsigned short* qb     = (unsigned short*)alloc(32ull*2048*64*2);
  unsigned short* kb     = (unsigned short*)alloc(32ull*2048*64*2);
  unsigned short* vt     = (unsigned short*)alloc(32ull*64*2048*2);
  unsigned short* mlp    = (unsigned short*)alloc(4096ull*4096*2);
  (void)ws_size; (void)in_sizes; (void)n_in; (void)out_size;

  k_conv_all<<<16384, 256, 0, stream>>>(qkv_w, proj_w, fc1_w, fc2_w, w_qkv, w_proj, w_fc1, w_fc2);

  k_ada<<<dim3(SIX_D/256, B_), 256, 0, stream>>>(cond, ada_w, ada_b, ada);
  k_norm_mod<<<B_*T_, 256, 0, stream>>>(x, norm1w, ada, 0, D_, h1);
  k_gemm_bt<EPI_BF16><<<dim3(3072/128, 4096/128), 256, 0, stream>>>(
      h1, w_qkv, B_*T_, 3*D_, D_, qkv_out, nullptr, nullptr, 0, nullptr);
  k_qkv_post<<<B_*T_*NH_, 64, 0, stream>>>(qkv_out, q_nw, k_nw, wptr, qb, kb);
  k_vtrans<<<dim3(T_/64, 32), 256, 0, stream>>>(qkv_out, vt);
  k_attn<<<dim3(T_/128, 32, 2), 256, 0, stream>>>(qb, kb, vt, opart, lpart);
  k_attn_comb<<<32*T_*16/256, 256, 0, stream>>>(opart, lpart, attn_o);
  k_gemm_bt64<EPI_RESID><<<dim3(1024/128, 4096/64), 256, 0, stream>>>(
      attn_o, w_proj, B_*T_, D_, D_, x1, x, ada, 2*D_, proj_b);
  k_norm_mod<<<B_*T_, 256, 0, stream>>>(x1, norm2w, ada, 3*D_, 4*D_, h1);
  k_gemm_fc1<<<dim3(HID_/64, 4096/128), 256, 0, stream>>>(h1, w_fc1, fc1_b, mlp);
  k_gemm_bt64<EPI_RESID><<<dim3(1024/128, 4096/64), 256, 0, stream>>>(
      mlp, w_fc2, B_*T_, D_, HID_, out, x1, ada, 5*D_, fc2_b);
}